// Round 5
// baseline (8720.431 us; speedup 1.0000x reference)
//
#include <hip/hip_runtime.h>
#include <hip/hip_bf16.h>

using bf16 = __hip_bfloat16;
typedef __attribute__((ext_vector_type(8))) short bf16x8;
typedef __attribute__((ext_vector_type(4))) float f32x4;

static constexpr int HD = 2048;   // hidden
static constexpr int BB = 512;    // batch
static constexpr int OD = 512;    // output dim
static constexpr int TT = 32;     // time steps
static constexpr int PS = 40;     // LDS row stride (gemm32 only)

#define MFMA(a, b, c) __builtin_amdgcn_mfma_f32_16x16x32_bf16((a), (b), (c), 0, 0, 0)

__device__ __forceinline__ bf16x8 ldg8b(const bf16* p) { return *(const bf16x8*)p; }

__device__ __forceinline__ bf16x8 cvt8(const float* p) {
  const float4 a = *(const float4*)p;
  const float4 b = *(const float4*)(p + 4);
  union { bf16x8 v; bf16 e[8]; } u;
  u.e[0] = __float2bfloat16(a.x); u.e[1] = __float2bfloat16(a.y);
  u.e[2] = __float2bfloat16(a.z); u.e[3] = __float2bfloat16(a.w);
  u.e[4] = __float2bfloat16(b.x); u.e[5] = __float2bfloat16(b.y);
  u.e[6] = __float2bfloat16(b.z); u.e[7] = __float2bfloat16(b.w);
  return u.v;
}

__global__ __launch_bounds__(256) void cvt_kernel(const float* __restrict__ s,
                                                  bf16* __restrict__ d, int n4) {
  const int i = blockIdx.x * 256 + threadIdx.x;
  if (i < n4) {
    const float4 v = ((const float4*)s)[i];
    union { unsigned long long u; bf16 e[4]; } o;
    o.e[0] = __float2bfloat16(v.x); o.e[1] = __float2bfloat16(v.y);
    o.e[2] = __float2bfloat16(v.z); o.e[3] = __float2bfloat16(v.w);
    *(unsigned long long*)(d + 4l * i) = o.u;
  }
}

// Barrier-free fused GRU cell. Block = 128m x 32n x 3 gates, 8 waves
// (wm 0..3 x wn 0..1), wave = 32m x 16n per gate. No LDS: A and W frags
// load global->VGPR (16-row x 64B gather, fully 64B-coalesced); waves
// sharing wm/wn hit the same lines in L1. Depth-4 rotating register
// prefetch; compiler emits fine-grained vmcnt — no barrier drain.
#define RUN_PHASE(Abase, Wbase, K, NS, ACCN)                                   \
  {                                                                            \
    const bf16* a0p = (Abase) + (long)(m0w + cl) * (K) + chunk;                \
    const bf16* a1p = a0p + 16l * (K);                                         \
    const bf16* w0p = (Wbase) + (long)(n0g + cl) * (K) + chunk;                \
    const bf16* w1p = w0p + (long)HD * (K);                                    \
    const bf16* w2p = w1p + (long)HD * (K);                                    \
    bf16x8 fa0[4], fa1[4], fw0[4], fw1[4], fw2[4];                             \
    _Pragma("unroll")                                                          \
    for (int i = 0; i < 4; ++i) {                                              \
      fa0[i] = ldg8b(a0p + i * 32); fa1[i] = ldg8b(a1p + i * 32);              \
      fw0[i] = ldg8b(w0p + i * 32); fw1[i] = ldg8b(w1p + i * 32);              \
      fw2[i] = ldg8b(w2p + i * 32);                                            \
    }                                                                          \
    for (int s = 0; s < (NS); s += 4) {                                        \
      _Pragma("unroll")                                                        \
      for (int u = 0; u < 4; ++u) {                                            \
        acc[0][0] = MFMA(fa0[u], fw0[u], acc[0][0]);                           \
        acc[0][1] = MFMA(fa1[u], fw0[u], acc[0][1]);                           \
        acc[1][0] = MFMA(fa0[u], fw1[u], acc[1][0]);                           \
        acc[1][1] = MFMA(fa1[u], fw1[u], acc[1][1]);                           \
        acc[ACCN][0] = MFMA(fa0[u], fw2[u], acc[ACCN][0]);                     \
        acc[ACCN][1] = MFMA(fa1[u], fw2[u], acc[ACCN][1]);                     \
        const int nxt = s + u + 4;                                             \
        if (nxt < (NS)) {                                                      \
          fa0[u] = ldg8b(a0p + (long)nxt * 32);                                \
          fa1[u] = ldg8b(a1p + (long)nxt * 32);                                \
          fw0[u] = ldg8b(w0p + (long)nxt * 32);                                \
          fw1[u] = ldg8b(w1p + (long)nxt * 32);                                \
          fw2[u] = ldg8b(w2p + (long)nxt * 32);                                \
        }                                                                      \
      }                                                                        \
    }                                                                          \
  }

__global__ __launch_bounds__(512, 2) void gru_cell_kernel(
    const bf16* __restrict__ Ax, int Kx,        // [B, Kx] bf16 layer input
    const bf16* __restrict__ Ahb,               // [B, H] bf16 h shadow
    const float* __restrict__ hprevf,           // [B, H] fp32 h master
    const bf16* __restrict__ Wih,               // [3H, Kx] bf16
    const bf16* __restrict__ Whh,               // [3H, H] bf16
    const float* __restrict__ bih, const float* __restrict__ bhh,
    float* __restrict__ houtf, bf16* __restrict__ houtb) {
  const int tid = threadIdx.x;
  const int lane = tid & 63;
  const int w = tid >> 6;                       // 0..7
  const int wm = w >> 1, wn = w & 1;
  const int bid = blockIdx.x;
  const int bm = (bid >> 3) & 3;                // 4 m-groups
  const int bn = (bid & 7) + 8 * (bid >> 5);    // 64 n-blocks, XCD-grouped
  const int m0w = bm * 128 + wm * 32;           // wave m base
  const int n0g = bn * 32 + wn * 16;            // wave per-gate n base
  const int cl = lane & 15;
  const int chunk = (lane >> 4) * 8;            // k elem offset in 32-slice

  // acc: 0=r, 1=z (both phases), 2=gx_n (A), 3=gh_n (B); [gate][m-frag]
  f32x4 acc[4][2];
#pragma unroll
  for (int a = 0; a < 4; ++a)
#pragma unroll
    for (int i = 0; i < 2; ++i) acc[a][i] = (f32x4){0.f, 0.f, 0.f, 0.f};

  RUN_PHASE(Ax, Wih, Kx, Kx >> 5, 2);           // gx accumulation
  RUN_PHASE(Ahb, Whh, HD, HD >> 5, 3);          // gh accumulation

  // C/D layout: col=lane&15, row=(lane>>4)*4+reg (m89-verified)
  const int q = lane >> 4;
  const int j = n0g + cl;
  const float bihr = bih[j], bihz = bih[j + HD], bihn = bih[j + 2 * HD];
  const float bhhr = bhh[j], bhhz = bhh[j + HD], bhhn = bhh[j + 2 * HD];
#pragma unroll
  for (int mi = 0; mi < 2; ++mi)
#pragma unroll
    for (int r = 0; r < 4; ++r) {
      const int b = m0w + mi * 16 + q * 4 + r;
      const float gr = acc[0][mi][r] + bihr + bhhr;
      const float gz = acc[1][mi][r] + bihz + bhhz;
      const float gnx = acc[2][mi][r] + bihn;
      const float gnh = acc[3][mi][r] + bhhn;
      const float rr = 1.f / (1.f + __expf(-gr));
      const float zz = 1.f / (1.f + __expf(-gz));
      const float nn = tanhf(gnx + rr * gnh);
      const float hp = hprevf[(long)b * HD + j];
      const float hn = (1.f - zz) * nn + zz * hp;
      houtf[(long)b * HD + j] = hn;
      houtb[(long)b * HD + j] = __float2bfloat16(hn);
    }
}

// Naive fp32 fallback cell (only if workspace too small for bf16 weights).
__global__ __launch_bounds__(256) void gru_cell_naive(
    const bf16* __restrict__ Ax, int Kx, const bf16* __restrict__ Ahb,
    const float* __restrict__ hprevf,
    const float* __restrict__ Wih, const float* __restrict__ Whh,
    const float* __restrict__ bih, const float* __restrict__ bhh,
    float* __restrict__ houtf, bf16* __restrict__ houtb) {
  const int idx = blockIdx.x * 256 + threadIdx.x;
  if (idx >= BB * HD) return;
  const int b = idx / HD, j = idx % HD;
  float gr = bih[j] + bhh[j], gz = bih[j + HD] + bhh[j + HD];
  float gnx = bih[j + 2 * HD], gnh = bhh[j + 2 * HD];
  for (int k = 0; k < Kx; ++k) {
    const float xv = __bfloat162float(Ax[(long)b * Kx + k]);
    gr += xv * Wih[(long)j * Kx + k];
    gz += xv * Wih[((long)j + HD) * Kx + k];
    gnx += xv * Wih[((long)j + 2 * HD) * Kx + k];
  }
  for (int k = 0; k < HD; ++k) {
    const float hv = __bfloat162float(Ahb[(long)b * HD + k]);
    gr += hv * Whh[(long)j * HD + k];
    gz += hv * Whh[((long)j + HD) * HD + k];
    gnh += hv * Whh[((long)j + 2 * HD) * HD + k];
  }
  const float rr = 1.f / (1.f + __expf(-gr));
  const float zz = 1.f / (1.f + __expf(-gz));
  const float nn = tanhf(gnx + rr * gnh);
  const float hp = hprevf[(long)b * HD + j];
  const float hn = (1.f - zz) * nn + zz * hp;
  houtf[(long)b * HD + j] = hn;
  houtb[(long)b * HD + j] = __float2bfloat16(hn);
}

// C = A @ W^T + bias, tile 32m x 64n, 4 waves (round-4 proven).
// mode 0: embedding — relu, scatter rows (b*2+l) into h0/h1 (fp32+bf16)
// mode 1: projection — preds[b,t,:] fp32 + xbuf bf16
__global__ __launch_bounds__(256) void gemm32_kernel(
    const void* __restrict__ A, int abf, const void* __restrict__ W, int wbf,
    const float* __restrict__ bias, int K, int mode, int t, int mshift,
    float* __restrict__ o0f, bf16* __restrict__ o0b,
    float* __restrict__ o1f, bf16* __restrict__ o1b,
    float* __restrict__ preds, bf16* __restrict__ xbuf) {
  __shared__ __align__(16) bf16 smem[(32 + 64) * PS];
  bf16* const sA = smem;
  bf16* const sW = smem + 32 * PS;
  const int tid = threadIdx.x;
  const int lane = tid & 63;
  const int wv = tid >> 6;
  const int wc = wv * 16;
  const int bid = blockIdx.x;
  const int i = bid >> 3;
  const int m0 = (i & ((1 << mshift) - 1)) * 32;
  const int n0 = ((bid & 7) + 8 * (i >> mshift)) * 64;
  const int nsteps = K >> 5;
  const int srow = tid >> 2, sch = tid & 3;

  f32x4 acc[2];
  acc[0] = (f32x4){0.f, 0.f, 0.f, 0.f};
  acc[1] = (f32x4){0.f, 0.f, 0.f, 0.f};

  bf16x8 pfA, pfW;
  auto loadr = [&](int s) {
    const int k = (s << 5) + sch * 8;
    if (tid < 128) {
      const long off = (long)(m0 + (tid >> 2)) * K + k;
      pfA = abf ? ldg8b((const bf16*)A + off) : cvt8((const float*)A + off);
    }
    const long off = (long)(n0 + srow) * K + k;
    pfW = wbf ? ldg8b((const bf16*)W + off) : cvt8((const float*)W + off);
  };
  auto store_lds = [&]() {
    if (tid < 128) *(bf16x8*)(sA + (tid >> 2) * PS + (tid & 3) * 8) = pfA;
    *(bf16x8*)(sW + srow * PS + sch * 8) = pfW;
  };
  auto frg = [&](const bf16* tl, int off) -> bf16x8 {
    return *(const bf16x8*)(tl + (off + (lane & 15)) * PS + (lane >> 4) * 8);
  };

  loadr(0);
  for (int s = 0; s < nsteps; ++s) {
    store_lds();
    __syncthreads();
    if (s + 1 < nsteps) loadr(s + 1);
    bf16x8 a0 = frg(sA, 0), a1 = frg(sA, 16);
    bf16x8 bw = frg(sW, wc);
    acc[0] = MFMA(a0, bw, acc[0]);
    acc[1] = MFMA(a1, bw, acc[1]);
    __syncthreads();
  }

  const int q = lane >> 4, cl = lane & 15;
  const int j = n0 + wc + cl;
  const float bj = bias[j];
#pragma unroll
  for (int mi = 0; mi < 2; ++mi)
#pragma unroll
    for (int r = 0; r < 4; ++r) {
      const int row = m0 + mi * 16 + q * 4 + r;
      float v = acc[mi][r] + bj;
      if (mode == 0) {
        v = fmaxf(v, 0.f);
        const int b = row >> 1, l = row & 1;    // x rows are (b, l) pairs
        if (l == 0) { o0f[(long)b * HD + j] = v; o0b[(long)b * HD + j] = __float2bfloat16(v); }
        else        { o1f[(long)b * HD + j] = v; o1b[(long)b * HD + j] = __float2bfloat16(v); }
      } else {
        preds[((long)row * TT + t) * OD + j] = v;
        xbuf[(long)row * OD + j] = __float2bfloat16(v);
      }
    }
}

extern "C" void kernel_launch(void* const* d_in, const int* in_sizes, int n_in,
                              void* d_out, int out_size, void* d_ws, size_t ws_size,
                              hipStream_t stream) {
  const float* x    = (const float*)d_in[0];
  const float* embW = (const float*)d_in[1];
  const float* embb = (const float*)d_in[2];
  const float* Wih0 = (const float*)d_in[3];
  const float* Whh0 = (const float*)d_in[4];
  const float* bih0 = (const float*)d_in[5];
  const float* bhh0 = (const float*)d_in[6];
  const float* Wih1 = (const float*)d_in[7];
  const float* Whh1 = (const float*)d_in[8];
  const float* bih1 = (const float*)d_in[9];
  const float* bhh1 = (const float*)d_in[10];
  const float* outW = (const float*)d_in[11];
  const float* outb = (const float*)d_in[12];
  float* preds = (float*)d_out;

  char* p = (char*)d_ws;
  const size_t HF = (size_t)BB * HD * 4;
  const size_t HB = (size_t)BB * HD * 2;
  float* h0f[2] = {(float*)p, (float*)(p + HF)}; p += 2 * HF;
  float* h1f[2] = {(float*)p, (float*)(p + HF)}; p += 2 * HF;
  bf16* h0b[2] = {(bf16*)p, (bf16*)(p + HB)}; p += 2 * HB;
  bf16* h1b[2] = {(bf16*)p, (bf16*)(p + HB)}; p += 2 * HB;
  bf16* xbuf = (bf16*)p; p += (size_t)BB * OD * 2;

  const int nE = 2048 * 1024, nI0 = 6144 * 512, nH = 6144 * 2048, nO = 512 * 2048;
  const size_t conv_bytes = 2ul * (nE + nI0 + 3ul * nH + nO);
  const bool big = ws_size >= (size_t)(p - (char*)d_ws) + conv_bytes;
  bf16 *embWc = nullptr, *Wih0c = nullptr, *Whh0c = nullptr,
       *Wih1c = nullptr, *Whh1c = nullptr, *outWc = nullptr;
  if (big) {
    embWc = (bf16*)p; p += 2ul * nE;
    Wih0c = (bf16*)p; p += 2ul * nI0;
    Whh0c = (bf16*)p; p += 2ul * nH;
    Wih1c = (bf16*)p; p += 2ul * nH;
    Whh1c = (bf16*)p; p += 2ul * nH;
    outWc = (bf16*)p; p += 2ul * nO;
    auto cv = [&](const float* s, bf16* d, int n) {
      cvt_kernel<<<(n / 4 + 255) / 256, 256, 0, stream>>>(s, d, n / 4);
    };
    cv(embW, embWc, nE); cv(Wih0, Wih0c, nI0); cv(Whh0, Whh0c, nH);
    cv(Wih1, Wih1c, nH); cv(Whh1, Whh1c, nH); cv(outW, outWc, nO);
  }
  const int wbf = big ? 1 : 0;
  const void* embWs = big ? (const void*)embWc : (const void*)embW;
  const void* outWs = big ? (const void*)outWc : (const void*)outW;

  hipMemsetAsync(xbuf, 0, (size_t)BB * OD * 2, stream);  // zero input, steps 0-1

  // embedding: x as [1024,1024] (rows b*2+l), 32 m-tiles x 32 n-tiles
  gemm32_kernel<<<1024, 256, 0, stream>>>(
      x, 0, embWs, wbf, embb, 1024, 0, 0, 5,
      h0f[0], h0b[0], h1f[0], h1b[0], nullptr, nullptr);

  for (int s = 0; s < 33; ++s) {
    const int cur = s & 1, nxt = cur ^ 1;
    if (big) {
      gru_cell_kernel<<<256, 512, 0, stream>>>(
          xbuf, OD, h0b[cur], h0f[cur], Wih0c, Whh0c, bih0, bhh0,
          h0f[nxt], h0b[nxt]);
      gru_cell_kernel<<<256, 512, 0, stream>>>(
          h0b[nxt], HD, h1b[cur], h1f[cur], Wih1c, Whh1c, bih1, bhh1,
          h1f[nxt], h1b[nxt]);
    } else {
      gru_cell_naive<<<(BB * HD + 255) / 256, 256, 0, stream>>>(
          xbuf, OD, h0b[cur], h0f[cur], Wih0, Whh0, bih0, bhh0,
          h0f[nxt], h0b[nxt]);
      gru_cell_naive<<<(BB * HD + 255) / 256, 256, 0, stream>>>(
          h0b[nxt], HD, h1b[cur], h1f[cur], Wih1, Whh1, bih1, bhh1,
          h1f[nxt], h1b[nxt]);
    }
    if (s >= 1)
      gemm32_kernel<<<128, 256, 0, stream>>>(
          h1b[nxt], 1, outWs, wbf, outb, HD, 1, s - 1, 4,
          nullptr, nullptr, nullptr, nullptr, preds, xbuf);
  }
}

// Round 6
// 3999.287 us; speedup vs baseline: 2.1805x; 2.1805x over previous
//
#include <hip/hip_runtime.h>
#include <hip/hip_bf16.h>

using bf16 = __hip_bfloat16;
typedef __attribute__((ext_vector_type(8))) short bf16x8;
typedef __attribute__((ext_vector_type(4))) float f32x4;

static constexpr int HD = 2048;   // hidden
static constexpr int BB = 512;    // batch
static constexpr int OD = 512;    // output dim
static constexpr int TT = 32;     // time steps

#define MFMA(a, b, c) __builtin_amdgcn_mfma_f32_16x16x32_bf16((a), (b), (c), 0, 0, 0)

__device__ __forceinline__ void gld16(const void* g, void* l) {
  __builtin_amdgcn_global_load_lds((const __attribute__((address_space(1))) void*)g,
                                   (__attribute__((address_space(3))) void*)l, 16, 0, 0);
}

// one-time fp32 -> bf16 conversion
__global__ __launch_bounds__(256) void cvt_kernel(const float* __restrict__ s,
                                                  bf16* __restrict__ d, int n4) {
  const int i = blockIdx.x * 256 + threadIdx.x;
  if (i < n4) {
    const float4 v = ((const float4*)s)[i];
    union { unsigned long long u; bf16 e[4]; } o;
    o.e[0] = __float2bfloat16(v.x); o.e[1] = __float2bfloat16(v.y);
    o.e[2] = __float2bfloat16(v.z); o.e[3] = __float2bfloat16(v.w);
    *(unsigned long long*)(d + 4l * i) = o.u;
  }
}

// Fused GRU cell, m97-style DMA staging, single barrier per K-step.
// Block: 128m x 32n x 3 gates, 4 waves; wave = 64m x 16n x 3 gates
// (12 MFMA, 7 ds_read_b128 per K-step). LDS double-buffered 2x14KB;
// DMA for step s+1 issues after the barrier of step s and drains at the
// next barrier (own-wave vmcnt), overlapping MFMA+LDS reads with staging.
#define CELL_STEP(NACC, STAGE_CALL)                                            \
  {                                                                            \
    __syncthreads();                                                           \
    STAGE_CALL;                                                                \
    const char* base = smem + buf * 14336;                                     \
    const char* aB = base + (wm * 64 + cl) * 64 + q16;                         \
    const char* wB = base + 8192 + (wn * 16 + cl) * 64 + q16;                  \
    bf16x8 a0 = *(const bf16x8*)(aB);                                          \
    bf16x8 a1 = *(const bf16x8*)(aB + 1024);                                   \
    bf16x8 a2 = *(const bf16x8*)(aB + 2048);                                   \
    bf16x8 a3 = *(const bf16x8*)(aB + 3072);                                   \
    bf16x8 w0 = *(const bf16x8*)(wB);                                          \
    bf16x8 w1 = *(const bf16x8*)(wB + 2048);                                   \
    bf16x8 w2 = *(const bf16x8*)(wB + 4096);                                   \
    acc[0][0] = MFMA(a0, w0, acc[0][0]);                                       \
    acc[0][1] = MFMA(a1, w0, acc[0][1]);                                       \
    acc[0][2] = MFMA(a2, w0, acc[0][2]);                                       \
    acc[0][3] = MFMA(a3, w0, acc[0][3]);                                       \
    acc[1][0] = MFMA(a0, w1, acc[1][0]);                                       \
    acc[1][1] = MFMA(a1, w1, acc[1][1]);                                       \
    acc[1][2] = MFMA(a2, w1, acc[1][2]);                                       \
    acc[1][3] = MFMA(a3, w1, acc[1][3]);                                       \
    acc[NACC][0] = MFMA(a0, w2, acc[NACC][0]);                                 \
    acc[NACC][1] = MFMA(a1, w2, acc[NACC][1]);                                 \
    acc[NACC][2] = MFMA(a2, w2, acc[NACC][2]);                                 \
    acc[NACC][3] = MFMA(a3, w2, acc[NACC][3]);                                 \
    buf ^= 1;                                                                  \
  }

__global__ __launch_bounds__(256) void gru_cell_kernel(
    const bf16* __restrict__ Ax, int Kx,        // [B, Kx] bf16 layer input
    const bf16* __restrict__ Ahb,               // [B, H] bf16 h shadow
    const float* __restrict__ hprevf,           // [B, H] fp32 h master
    const bf16* __restrict__ Wih,               // [3H, Kx] bf16
    const bf16* __restrict__ Whh,               // [3H, H] bf16
    const float* __restrict__ bih, const float* __restrict__ bhh,
    float* __restrict__ houtf, bf16* __restrict__ houtb) {
  __shared__ __align__(1024) char smem[2 * 14336];  // [A 8KB | W 6KB] x 2
  const int tid = threadIdx.x;
  const int lane = tid & 63;
  const int w = __builtin_amdgcn_readfirstlane(tid >> 6);
  const int wm = w >> 1, wn = w & 1;
  const int bid = blockIdx.x;
  const int rest = bid >> 3;
  const int m0 = (rest >> 3) * 128;               // 4 m-groups
  const int n0 = ((bid & 7) * 8 + (rest & 7)) * 32;  // same-n -> same XCD
  const int lr = lane >> 2, lc = (lane & 3) << 3;
  const int cl = lane & 15, q16 = (lane >> 4) * 16, q = lane >> 4;
  const int nsa = Kx >> 5, nsb = HD >> 5;

  // acc: 0=r, 1=z (both phases), 2=gx_n (A), 3=gh_n (B); [gate][m-frag]
  f32x4 acc[4][4];
#pragma unroll
  for (int a = 0; a < 4; ++a)
#pragma unroll
    for (int i = 0; i < 4; ++i) acc[a][i] = (f32x4){0.f, 0.f, 0.f, 0.f};

  // stage K-slice s of (Ap,Wp) into buffer b. waves 0-1: A (4 issues each,
  // 16 rows x 64B = 1KB contiguous per issue); waves 2-3: W (3 issues each).
  auto stage = [&](const bf16* Ap, const bf16* Wp, int K, int s, int b) {
    char* base = smem + b * 14336;
    const int k0 = (s << 5) + lc;
    if (w < 2) {
#pragma unroll
      for (int it = 0; it < 4; ++it) {
        const int r = (w * 4 + it) * 16;
        gld16(Ap + (long)(m0 + r + lr) * K + k0, base + r * 64);
      }
    } else {
#pragma unroll
      for (int it = 0; it < 3; ++it) {
        const int jj = (w - 2) * 3 + it;       // 0..5: gate jj>>1, half jj&1
        gld16(Wp + ((long)(jj >> 1) * HD + n0 + (jj & 1) * 16 + lr) * K + k0,
              base + 8192 + jj * 1024);
      }
    }
  };

  stage(Ax, Wih, Kx, 0, 0);
  int buf = 0;
  for (int s = 0; s < nsa; ++s)                  // phase A: x @ Wih^T
    CELL_STEP(2, if (s + 1 < nsa) stage(Ax, Wih, Kx, s + 1, buf ^ 1);
                 else stage(Ahb, Whh, HD, 0, buf ^ 1));
  for (int s = 0; s < nsb; ++s)                  // phase B: h @ Whh^T
    CELL_STEP(3, if (s + 1 < nsb) stage(Ahb, Whh, HD, s + 1, buf ^ 1));

  // C/D layout: col=lane&15, row=(lane>>4)*4+reg (m89-verified)
  const int j = n0 + wn * 16 + cl;
  const float bihr = bih[j], bihz = bih[j + HD], bihn = bih[j + 2 * HD];
  const float bhhr = bhh[j], bhhz = bhh[j + HD], bhhn = bhh[j + 2 * HD];
#pragma unroll
  for (int mi = 0; mi < 4; ++mi)
#pragma unroll
    for (int r = 0; r < 4; ++r) {
      const int b = m0 + wm * 64 + mi * 16 + q * 4 + r;
      const float gr = acc[0][mi][r] + bihr + bhhr;
      const float gz = acc[1][mi][r] + bihz + bhhz;
      const float gnx = acc[2][mi][r] + bihn;
      const float gnh = acc[3][mi][r] + bhhn;
      const float rr = 1.f / (1.f + __expf(-gr));
      const float zz = 1.f / (1.f + __expf(-gz));
      const float nn = tanhf(gnx + rr * gnh);
      const float hp = hprevf[(long)b * HD + j];
      const float hn = (1.f - zz) * nn + zz * hp;
      houtf[(long)b * HD + j] = hn;
      houtb[(long)b * HD + j] = __float2bfloat16(hn);
    }
}

// C = A @ W^T + bias, tile 64m x 64n, 4 waves (wave = 64m x 16n), same
// DMA staging + single-barrier dbuf scheme. A,W bf16.
// mode 0: embedding — relu, scatter rows (b*2+l) into h0/h1 (fp32+bf16)
// mode 1: projection — preds[b,t,:] fp32 + xbuf bf16
__global__ __launch_bounds__(256) void gemm64_kernel(
    const bf16* __restrict__ A, const bf16* __restrict__ W,
    const float* __restrict__ bias, int K, int mode, int t, int nbits,
    float* __restrict__ o0f, bf16* __restrict__ o0b,
    float* __restrict__ o1f, bf16* __restrict__ o1b,
    float* __restrict__ preds, bf16* __restrict__ xbuf) {
  __shared__ __align__(1024) char smem[2 * 8192];  // [A 4KB | W 4KB] x 2
  const int tid = threadIdx.x;
  const int lane = tid & 63;
  const int w = __builtin_amdgcn_readfirstlane(tid >> 6);
  const int bid = blockIdx.x;
  const int rest = bid >> 3;
  const int m0 = (rest >> nbits) * 64;
  const int n0 = (((bid & 7) << nbits) + (rest & ((1 << nbits) - 1))) * 64;
  const int lr = lane >> 2, lc = (lane & 3) << 3;
  const int cl = lane & 15, q16 = (lane >> 4) * 16, q = lane >> 4;
  const int ns = K >> 5;

  f32x4 acc[4];
#pragma unroll
  for (int i = 0; i < 4; ++i) acc[i] = (f32x4){0.f, 0.f, 0.f, 0.f};

  auto stage = [&](int s, int b) {
    char* base = smem + b * 8192;
    const int k0 = (s << 5) + lc;
    if (w < 2) {
#pragma unroll
      for (int it = 0; it < 2; ++it) {
        const int r = (w * 2 + it) * 16;
        gld16(A + (long)(m0 + r + lr) * K + k0, base + r * 64);
      }
    } else {
#pragma unroll
      for (int it = 0; it < 2; ++it) {
        const int jj = (w - 2) * 2 + it;       // 0..3
        gld16(W + (long)(n0 + jj * 16 + lr) * K + k0, base + 4096 + jj * 1024);
      }
    }
  };

  stage(0, 0);
  int buf = 0;
  for (int s = 0; s < ns; ++s) {
    __syncthreads();
    if (s + 1 < ns) stage(s + 1, buf ^ 1);
    const char* base = smem + buf * 8192;
    const char* aB = base + cl * 64 + q16;
    bf16x8 a0 = *(const bf16x8*)(aB);
    bf16x8 a1 = *(const bf16x8*)(aB + 1024);
    bf16x8 a2 = *(const bf16x8*)(aB + 2048);
    bf16x8 a3 = *(const bf16x8*)(aB + 3072);
    bf16x8 wf = *(const bf16x8*)(base + 4096 + (w * 16 + cl) * 64 + q16);
    acc[0] = MFMA(a0, wf, acc[0]);
    acc[1] = MFMA(a1, wf, acc[1]);
    acc[2] = MFMA(a2, wf, acc[2]);
    acc[3] = MFMA(a3, wf, acc[3]);
    buf ^= 1;
  }

  const int j = n0 + w * 16 + cl;
  const float bj = bias[j];
#pragma unroll
  for (int mi = 0; mi < 4; ++mi)
#pragma unroll
    for (int r = 0; r < 4; ++r) {
      const int row = m0 + mi * 16 + q * 4 + r;
      float v = acc[mi][r] + bj;
      if (mode == 0) {
        v = fmaxf(v, 0.f);
        const int b = row >> 1, l = row & 1;   // x rows are (b, l) pairs
        if (l == 0) { o0f[(long)b * HD + j] = v; o0b[(long)b * HD + j] = __float2bfloat16(v); }
        else        { o1f[(long)b * HD + j] = v; o1b[(long)b * HD + j] = __float2bfloat16(v); }
      } else {
        preds[((long)row * TT + t) * OD + j] = v;
        xbuf[(long)row * OD + j] = __float2bfloat16(v);
      }
    }
}

// ---- naive fallbacks (only if workspace too small for bf16 weights) ----
__global__ __launch_bounds__(256) void gru_cell_naive(
    const bf16* __restrict__ Ax, int Kx, const bf16* __restrict__ Ahb,
    const float* __restrict__ hprevf,
    const float* __restrict__ Wih, const float* __restrict__ Whh,
    const float* __restrict__ bih, const float* __restrict__ bhh,
    float* __restrict__ houtf, bf16* __restrict__ houtb) {
  const int idx = blockIdx.x * 256 + threadIdx.x;
  if (idx >= BB * HD) return;
  const int b = idx / HD, j = idx % HD;
  float gr = bih[j] + bhh[j], gz = bih[j + HD] + bhh[j + HD];
  float gnx = bih[j + 2 * HD], gnh = bhh[j + 2 * HD];
  for (int k = 0; k < Kx; ++k) {
    const float xv = __bfloat162float(Ax[(long)b * Kx + k]);
    gr += xv * Wih[(long)j * Kx + k];
    gz += xv * Wih[((long)j + HD) * Kx + k];
    gnx += xv * Wih[((long)j + 2 * HD) * Kx + k];
  }
  for (int k = 0; k < HD; ++k) {
    const float hv = __bfloat162float(Ahb[(long)b * HD + k]);
    gr += hv * Whh[(long)j * HD + k];
    gz += hv * Whh[((long)j + HD) * HD + k];
    gnh += hv * Whh[((long)j + 2 * HD) * HD + k];
  }
  const float rr = 1.f / (1.f + __expf(-gr));
  const float zz = 1.f / (1.f + __expf(-gz));
  const float nn = tanhf(gnx + rr * gnh);
  const float hp = hprevf[(long)b * HD + j];
  const float hn = (1.f - zz) * nn + zz * hp;
  houtf[(long)b * HD + j] = hn;
  houtb[(long)b * HD + j] = __float2bfloat16(hn);
}

__global__ __launch_bounds__(256) void naive_gemm(
    const void* __restrict__ A, int abf, const float* __restrict__ W,
    const float* __restrict__ bias, int N, int K, int mode, int t,
    float* __restrict__ o0f, bf16* __restrict__ o0b,
    float* __restrict__ o1f, bf16* __restrict__ o1b,
    float* __restrict__ preds, bf16* __restrict__ xbuf) {
  const long idx = (long)blockIdx.x * 256 + threadIdx.x;
  const int row = idx / N, j = idx % N;
  float v = bias[j];
  for (int k = 0; k < K; ++k) {
    const float av = abf ? __bfloat162float(((const bf16*)A)[(long)row * K + k])
                         : ((const float*)A)[(long)row * K + k];
    v += av * W[(long)j * K + k];
  }
  if (mode == 0) {
    v = fmaxf(v, 0.f);
    const int b = row >> 1, l = row & 1;
    if (l == 0) { o0f[(long)b * HD + j] = v; o0b[(long)b * HD + j] = __float2bfloat16(v); }
    else        { o1f[(long)b * HD + j] = v; o1b[(long)b * HD + j] = __float2bfloat16(v); }
  } else {
    preds[((long)row * TT + t) * OD + j] = v;
    xbuf[(long)row * OD + j] = __float2bfloat16(v);
  }
}

extern "C" void kernel_launch(void* const* d_in, const int* in_sizes, int n_in,
                              void* d_out, int out_size, void* d_ws, size_t ws_size,
                              hipStream_t stream) {
  const float* x    = (const float*)d_in[0];
  const float* embW = (const float*)d_in[1];
  const float* embb = (const float*)d_in[2];
  const float* Wih0 = (const float*)d_in[3];
  const float* Whh0 = (const float*)d_in[4];
  const float* bih0 = (const float*)d_in[5];
  const float* bhh0 = (const float*)d_in[6];
  const float* Wih1 = (const float*)d_in[7];
  const float* Whh1 = (const float*)d_in[8];
  const float* bih1 = (const float*)d_in[9];
  const float* bhh1 = (const float*)d_in[10];
  const float* outW = (const float*)d_in[11];
  const float* outb = (const float*)d_in[12];
  float* preds = (float*)d_out;

  char* p = (char*)d_ws;
  const size_t HF = (size_t)BB * HD * 4;
  const size_t HB = (size_t)BB * HD * 2;
  float* h0f[2] = {(float*)p, (float*)(p + HF)}; p += 2 * HF;
  float* h1f[2] = {(float*)p, (float*)(p + HF)}; p += 2 * HF;
  bf16* h0b[2] = {(bf16*)p, (bf16*)(p + HB)}; p += 2 * HB;
  bf16* h1b[2] = {(bf16*)p, (bf16*)(p + HB)}; p += 2 * HB;
  bf16* xbuf = (bf16*)p; p += (size_t)BB * OD * 2;

  const int nE = 2048 * 1024, nI0 = 6144 * 512, nH = 6144 * 2048,
            nO = 512 * 2048, nX = 1024 * 1024;
  const size_t conv_bytes = 2ul * (nE + nI0 + 3ul * nH + nO + nX);
  const bool big = ws_size >= (size_t)(p - (char*)d_ws) + conv_bytes;

  hipMemsetAsync(xbuf, 0, (size_t)BB * OD * 2, stream);  // zero input, steps 0-1

  if (big) {
    bf16* embWc = (bf16*)p; p += 2ul * nE;
    bf16* Wih0c = (bf16*)p; p += 2ul * nI0;
    bf16* Whh0c = (bf16*)p; p += 2ul * nH;
    bf16* Wih1c = (bf16*)p; p += 2ul * nH;
    bf16* Whh1c = (bf16*)p; p += 2ul * nH;
    bf16* outWc = (bf16*)p; p += 2ul * nO;
    bf16* xbf   = (bf16*)p; p += 2ul * nX;
    auto cv = [&](const float* s, bf16* d, int n) {
      cvt_kernel<<<(n / 4 + 255) / 256, 256, 0, stream>>>(s, d, n / 4);
    };
    cv(embW, embWc, nE); cv(Wih0, Wih0c, nI0); cv(Whh0, Whh0c, nH);
    cv(Wih1, Wih1c, nH); cv(Whh1, Whh1c, nH); cv(outW, outWc, nO);
    cv(x, xbf, nX);

    // embedding: xbf [1024,1024] -> h0/h1; 16 m-tiles x 32 n-tiles
    gemm64_kernel<<<512, 256, 0, stream>>>(
        xbf, embWc, embb, 1024, 0, 0, 2,
        h0f[0], h0b[0], h1f[0], h1b[0], nullptr, nullptr);

    for (int s = 0; s < 33; ++s) {
      const int cur = s & 1, nxt = cur ^ 1;
      gru_cell_kernel<<<256, 256, 0, stream>>>(
          xbuf, OD, h0b[cur], h0f[cur], Wih0c, Whh0c, bih0, bhh0,
          h0f[nxt], h0b[nxt]);
      gru_cell_kernel<<<256, 256, 0, stream>>>(
          h0b[nxt], HD, h1b[cur], h1f[cur], Wih1c, Whh1c, bih1, bhh1,
          h1f[nxt], h1b[nxt]);
      if (s >= 1)
        gemm64_kernel<<<64, 256, 0, stream>>>(
            h1b[nxt], outWc, outb, HD, 1, s - 1, 0,
            nullptr, nullptr, nullptr, nullptr, preds, xbuf);
    }
  } else {
    naive_gemm<<<(1024 * 2048) / 256, 256, 0, stream>>>(
        x, 0, embW, embb, 2048, 1024, 0, 0,
        h0f[0], h0b[0], h1f[0], h1b[0], nullptr, nullptr);
    for (int s = 0; s < 33; ++s) {
      const int cur = s & 1, nxt = cur ^ 1;
      gru_cell_naive<<<(BB * HD + 255) / 256, 256, 0, stream>>>(
          xbuf, OD, h0b[cur], h0f[cur], Wih0, Whh0, bih0, bhh0,
          h0f[nxt], h0b[nxt]);
      gru_cell_naive<<<(BB * HD + 255) / 256, 256, 0, stream>>>(
          h0b[nxt], HD, h1b[cur], h1f[cur], Wih1, Whh1, bih1, bhh1,
          h1f[nxt], h1b[nxt]);
      if (s >= 1)
        naive_gemm<<<(512 * 512) / 256, 256, 0, stream>>>(
            h1b[nxt], 1, outW, outb, 512, 2048, 1, s - 1,
            nullptr, nullptr, nullptr, nullptr, preds, xbuf);
    }
  }
}